// Round 20
// baseline (1876.943 us; speedup 1.0000x reference)
//
#include <hip/hip_runtime.h>

#define M_DIM 8192
#define K_DIM 4096
#define N_DIM 11008
#define XSCALE 20.0f

typedef int i32x4  __attribute__((ext_vector_type(4)));
typedef unsigned char uchar;

// ---------- pre-pass 1: x fp32 -> i8 (round(x*20), clamp +-127) + exact int row sums ----------
__global__ __launch_bounds__(256) void k_quant_x(const float4* __restrict__ x,
                                                 int4* __restrict__ xq,
                                                 float* __restrict__ rs) {
    __shared__ int sred[4];
    const int row = blockIdx.x;
    const int t = threadIdx.x;
    const float4* src = x + (size_t)row * (K_DIM / 4) + t * 4;
    int o[4];
    int acc = 0;
#pragma unroll
    for (int c = 0; c < 4; ++c) {
        float4 v = src[c];
        int b0 = __float2int_rn(fmaxf(fminf(v.x * XSCALE, 127.f), -127.f));
        int b1 = __float2int_rn(fmaxf(fminf(v.y * XSCALE, 127.f), -127.f));
        int b2 = __float2int_rn(fmaxf(fminf(v.z * XSCALE, 127.f), -127.f));
        int b3 = __float2int_rn(fmaxf(fminf(v.w * XSCALE, 127.f), -127.f));
        acc += b0 + b1 + b2 + b3;
        o[c] = (b0 & 255) | ((b1 & 255) << 8) | ((b2 & 255) << 16) | ((b3 & 255) << 24);
    }
    xq[(size_t)row * 256 + t] = make_int4(o[0], o[1], o[2], o[3]);
#pragma unroll
    for (int off = 32; off >= 1; off >>= 1) acc += __shfl_down(acc, off);
    if ((t & 63) == 0) sred[t >> 6] = acc;
    __syncthreads();
    if (t == 0) rs[row] = (float)(sred[0] + sred[1] + sred[2] + sred[3]);
}

// ---------- pre-pass 2: qweight int32 (0..15) -> packed i8 ----------
__global__ __launch_bounds__(256) void k_pack_w(const int4* __restrict__ q, int4* __restrict__ wq) {
    size_t i = (size_t)blockIdx.x * 256 + threadIdx.x;   // 16 elems per thread
    int4 a = q[i * 4], b = q[i * 4 + 1], c = q[i * 4 + 2], d = q[i * 4 + 3];
    int4 o;
    o.x = a.x | (a.y << 8) | (a.z << 16) | (a.w << 24);
    o.y = b.x | (b.y << 8) | (b.z << 16) | (b.w << 24);
    o.z = c.x | (c.y << 8) | (c.z << 16) | (c.w << 24);
    o.w = d.x | (d.y << 8) | (d.z << 16) | (d.w << 24);
    wq[i] = o;
}

// ---------- 256x256 i8 GEMM, 4 waves x 128x128 wave-tiles (min LDS traffic) ----------
// S[m][n] = sum_k X[m][k]*Q[n][k] (exact);  y = (s/20)*S - (s*zp/20)*RS[m] + bias
// LDS reads/CU/tile: 128 b128-insts (vs 192 at 8x128x64) -- the binding serial term.
// R17/R19 failed from MACRO VARIABLE CAPTURE: STAGE's inner row-group loop was named `g`,
// shadowing GROUP's K-tile parameter `g` in the source-address expression (staged tiles
// 2..5's columns forever). Inner loop vars renamed hh/rg; no other captures (audited).
//   batch @P4(t-1): aF0(8) | bF0(8) | bF1(8)
//   P1: lgkm(0) -> 32 MFMA(0,0)
//   P2: 32 MFMA(0,1) [batch already drained] -> issue aF1(t) -> BAR
//   P3: stage B(t+2)->buf; lgkm(0) -> 32 MFMA(1,1) -> BAR
//   P4: stage A(t+2)->buf; vmcnt(16) [publish t+1] -> BAR -> 32 MFMA(1,0) -> batch(t+1)
// Swizzle: 16B chunk c of row r at slot c^(r&7) (measured 0 conflicts, R8/R14).
using gcptr = const __attribute__((address_space(1))) void*;
using lptr  = __attribute__((address_space(3))) void*;
#define GLD16(gp, lp) __builtin_amdgcn_global_load_lds((gcptr)(gp), (lptr)(lp), 16, 0, 0)
#define BAR() asm volatile("s_barrier" ::: "memory")
#define SB0() __builtin_amdgcn_sched_barrier(0)
#define LGKM0() do { asm volatile("s_waitcnt lgkmcnt(0)" ::: "memory"); SB0(); } while (0)
#define VMW16() asm volatile("s_waitcnt vmcnt(16)" ::: "memory")
#define VMW0() asm volatile("s_waitcnt vmcnt(0)" ::: "memory")

__global__ __launch_bounds__(256, 1) void k_gemm(const uchar* __restrict__ A,
                                                 const uchar* __restrict__ B,
                                                 const float* __restrict__ rs,
                                                 const float* __restrict__ sc,
                                                 const float* __restrict__ zp,
                                                 const float* __restrict__ bias,
                                                 float* __restrict__ C) {
    constexpr int NT = K_DIM / 128;             // 32 K-tiles of BK=128 bytes
    constexpr int NBM = M_DIM / 256;            // 32
    constexpr int NWG = NBM * (N_DIM / 256);    // 1376, % 8 == 0

    __shared__ uchar sA[2][32768];              // 2 halves x 128 rows x 128 B
    __shared__ uchar sB[2][32768];

    // XCD-aware bijective swizzle
    int id = (blockIdx.x & 7) * (NWG / 8) + (blockIdx.x >> 3);
    const int bm = id & (NBM - 1);
    const int bn = id >> 5;

    const int tid = threadIdx.x;
    const int lane = tid & 63;
    const int w  = tid >> 6;     // wave 0..3
    const int wr = w >> 1;       // 0..1 (M): 128 rows
    const int wc = w & 1;        // 0..1 (N): 128 cols
    const int l15 = lane & 15;

    // ---- staging source (pre-swizzled: c_src = c_lds ^ (row&7); +32-row groups keep row&7) ----
    const int trow = tid >> 3;                                   // 0..31
    const int scol = ((tid & 7) ^ (trow & 7)) * 16;
    const uchar* aBase = A + (size_t)(bm * 256 + trow) * K_DIM + scol;
    const uchar* bBase = B + (size_t)(bn * 256 + trow) * K_DIM + scol;
    const int ldsW = w * 1024;                                   // wave rows w*8..w*8+7

    // stage full 256-row operand of tile kt: 2 halves x 4 row-groups = 8 GLD16/thread
    // (inner loop vars hh/rg -- MUST NOT shadow caller expressions)
#define STAGE_A(kt, sbuf) do { if ((kt) < NT) { \
        _Pragma("unroll") for (int hh = 0; hh < 2; ++hh) \
        _Pragma("unroll") for (int rg = 0; rg < 4; ++rg) \
            GLD16(aBase + (size_t)(hh * 128 + rg * 32) * K_DIM + (size_t)(kt) * 128, \
                  &sA[sbuf][hh * 16384 + rg * 4096 + ldsW]); } } while (0)
#define STAGE_B(kt, sbuf) do { if ((kt) < NT) { \
        _Pragma("unroll") for (int hh = 0; hh < 2; ++hh) \
        _Pragma("unroll") for (int rg = 0; rg < 4; ++rg) \
            GLD16(bBase + (size_t)(hh * 128 + rg * 32) * K_DIM + (size_t)(kt) * 128, \
                  &sB[sbuf][hh * 16384 + rg * 4096 + ldsW]); } } while (0)

    // ---- ds_read lane addressing (swizzled, 16-row frags; zero-conflict geometry) ----
    const int cb  = lane >> 4;                         // chunk selector 0..3
    const int swz = lane & 7;                          // row&7 for this lane
#define CHUNK(ks) ((((ks) * 4 + cb) ^ swz) * 16)
    const int aHalf = wr * 16384;                      // wave reads ONLY its half
    const int bHalf = wc * 16384;

    i32x4 aF[4][2];            // current mq: 4 m-frags x 2 ks (32 VGPR)
    i32x4 bF[2][4][2];         // BOTH nq sets: 2 x 4 n-frags x 2 ks (64 VGPR)
    i32x4 acc[8][8];           // 8 m x 8 n frags (256 regs)
#pragma unroll
    for (int j = 0; j < 8; ++j)
#pragma unroll
        for (int i = 0; i < 8; ++i) acc[j][i] = (i32x4){0, 0, 0, 0};

#define LDA(mq, buf) do { \
    _Pragma("unroll") for (int jj = 0; jj < 4; ++jj) \
    _Pragma("unroll") for (int ks = 0; ks < 2; ++ks) \
        aF[jj][ks] = *(const i32x4*)&sA[buf][aHalf + ((mq) * 64 + jj * 16 + l15) * 128 + CHUNK(ks)]; \
    } while (0)
#define LDB(nq, buf) do { \
    _Pragma("unroll") for (int ii = 0; ii < 4; ++ii) \
    _Pragma("unroll") for (int ks = 0; ks < 2; ++ks) \
        bF[nq][ii][ks] = *(const i32x4*)&sB[buf][bHalf + ((nq) * 64 + ii * 16 + l15) * 128 + CHUNK(ks)]; \
    } while (0)
#define MFMA_Q(mq, nq) do { \
    __builtin_amdgcn_s_setprio(1); \
    _Pragma("unroll") for (int ks = 0; ks < 2; ++ks) \
    _Pragma("unroll") for (int jj = 0; jj < 4; ++jj) \
    _Pragma("unroll") for (int ii = 0; ii < 4; ++ii) \
        acc[(mq) * 4 + jj][(nq) * 4 + ii] = __builtin_amdgcn_mfma_i32_16x16x64_i8( \
            aF[jj][ks], bF[nq][ii][ks], acc[(mq) * 4 + jj][(nq) * 4 + ii], 0, 0, 0); \
    __builtin_amdgcn_s_setprio(0); \
    SB0(); \
    } while (0)

    // ---- prologue: stage tiles 0,1; publish t0; prime batch(0) ----
    STAGE_B(0, 0); STAGE_A(0, 0);
    STAGE_B(1, 1); STAGE_A(1, 1);
    VMW16();                   // drains t0's 16; t1's 16 in flight
    BAR();
    LDA(0, 0); SB0();
    LDB(0, 0); SB0();
    LDB(1, 0);

    // ---- main loop: 3 barriers/tile ----
#define GROUP(g, buf) do { \
    /* P1: Q(0,0); drain the whole 24-read batch */ \
    LGKM0(); \
    MFMA_Q(0, 0); \
    /* P2: Q(0,1); then reload aF with mq=1 */ \
    MFMA_Q(0, 1); \
    LDA(1, buf); \
    BAR(); \
    /* P3: all B reads drained block-wide -> stage B(t+2); Q(1,1) */ \
    STAGE_B((g) + 2, buf); \
    LGKM0(); \
    MFMA_Q(1, 1); \
    BAR(); \
    /* P4: all A reads drained -> stage A(t+2); publish t+1; Q(1,0); next batch */ \
    STAGE_A((g) + 2, buf); \
    if ((g) >= NT - 2) { VMW0(); } else { VMW16(); } \
    BAR(); \
    MFMA_Q(1, 0); \
    if ((g) + 1 < NT) { \
        LDA(0, (buf) ^ 1); SB0(); \
        LDB(0, (buf) ^ 1); SB0(); \
        LDB(1, (buf) ^ 1); \
    } \
    } while (0)

    for (int g = 0; g < NT; g += 2) {
        GROUP(g, 0);
        GROUP(g + 1, 1);
    }

    // ---- epilogue: y = fs*S - fz*RS[row] + bias ----
    const float inv = 1.0f / XSCALE;
    float fsv[8], fzv[8], bvv[8];
    int colv[8];
#pragma unroll
    for (int i = 0; i < 8; ++i) {
        colv[i] = bn * 256 + wc * 128 + i * 16 + l15;
        fsv[i] = sc[colv[i]] * inv;
        fzv[i] = fsv[i] * zp[colv[i]];
        bvv[i] = bias[colv[i]];
    }
#pragma unroll
    for (int j = 0; j < 8; ++j) {
        const int rowbase = bm * 256 + wr * 128 + j * 16 + ((lane >> 4) << 2);
#pragma unroll
        for (int r = 0; r < 4; ++r) {
            const int row = rowbase + r;
            const float rsv = rs[row];
            float* cp = C + (size_t)row * N_DIM;
#pragma unroll
            for (int i = 0; i < 8; ++i)
                cp[colv[i]] = fsv[i] * (float)acc[j][i][r] - fzv[i] * rsv + bvv[i];
        }
    }
#undef GROUP
#undef MFMA_Q
#undef LDA
#undef LDB
#undef CHUNK
#undef STAGE_A
#undef STAGE_B
}

// ---------- fallback (ws too small): classic 16x16 fp32 tiled GEMM ----------
__global__ __launch_bounds__(256) void k_fb(const float* __restrict__ x, const int* __restrict__ q,
                                            const float* __restrict__ sc, const float* __restrict__ zp,
                                            const float* __restrict__ bias, float* __restrict__ C) {
    __shared__ float sX[16][17];
    __shared__ float sW[16][17];
    int tx = threadIdx.x & 15, ty = threadIdx.x >> 4;
    int m0 = blockIdx.y * 16, n0 = blockIdx.x * 16;
    int o = n0 + ty;
    float s = sc[o], z = zp[o];
    float acc = 0.f;
    for (int k0 = 0; k0 < K_DIM; k0 += 16) {
        sX[ty][tx] = x[(size_t)(m0 + ty) * K_DIM + k0 + tx];
        sW[ty][tx] = ((float)q[(size_t)o * K_DIM + k0 + tx] - z) * s;
        __syncthreads();
#pragma unroll
        for (int kk = 0; kk < 16; ++kk) acc += sX[ty][kk] * sW[tx][kk];
        __syncthreads();
    }
    C[(size_t)(m0 + ty) * N_DIM + n0 + tx] = acc + bias[n0 + tx];
}

extern "C" void kernel_launch(void* const* d_in, const int* in_sizes, int n_in,
                              void* d_out, int out_size, void* d_ws, size_t ws_size,
                              hipStream_t stream) {
    const float* x    = (const float*)d_in[0];
    const int*   qw   = (const int*)d_in[1];
    const float* sc   = (const float*)d_in[2];
    const float* zp   = (const float*)d_in[3];
    const float* bias = (const float*)d_in[4];
    float* out = (float*)d_out;

    const size_t xq_bytes = (size_t)M_DIM * K_DIM;        // 33,554,432
    const size_t wq_bytes = (size_t)N_DIM * K_DIM;        // 45,088,768
    const size_t rs_bytes = (size_t)M_DIM * 4;            // 32,768
    if (ws_size >= xq_bytes + wq_bytes + rs_bytes) {
        uchar* xq = (uchar*)d_ws;
        uchar* wq = xq + xq_bytes;
        float* rs = (float*)(wq + wq_bytes);
        k_quant_x<<<M_DIM, 256, 0, stream>>>((const float4*)x, (int4*)xq, rs);
        k_pack_w<<<N_DIM, 256, 0, stream>>>((const int4*)qw, (int4*)wq);
        k_gemm<<<(M_DIM / 256) * (N_DIM / 256), 256, 0, stream>>>(xq, wq, rs, sc, zp, bias, out);
    } else {
        dim3 g(N_DIM / 16, M_DIM / 16);
        k_fb<<<g, 256, 0, stream>>>(x, qw, sc, zp, bias, out);
    }
}

// Round 21
// 488.833 us; speedup vs baseline: 3.8396x; 3.8396x over previous
//
#include <hip/hip_runtime.h>

#define M_DIM 8192
#define K_DIM 4096
#define N_DIM 11008
#define XSCALE 20.0f

typedef int i32x4  __attribute__((ext_vector_type(4)));
typedef unsigned char uchar;

// ---------- pre-pass 1: x fp32 -> i8 (round(x*20), clamp +-127) + exact int row sums ----------
__global__ __launch_bounds__(256) void k_quant_x(const float4* __restrict__ x,
                                                 int4* __restrict__ xq,
                                                 float* __restrict__ rs) {
    __shared__ int sred[4];
    const int row = blockIdx.x;
    const int t = threadIdx.x;
    const float4* src = x + (size_t)row * (K_DIM / 4) + t * 4;
    int o[4];
    int acc = 0;
#pragma unroll
    for (int c = 0; c < 4; ++c) {
        float4 v = src[c];
        int b0 = __float2int_rn(fmaxf(fminf(v.x * XSCALE, 127.f), -127.f));
        int b1 = __float2int_rn(fmaxf(fminf(v.y * XSCALE, 127.f), -127.f));
        int b2 = __float2int_rn(fmaxf(fminf(v.z * XSCALE, 127.f), -127.f));
        int b3 = __float2int_rn(fmaxf(fminf(v.w * XSCALE, 127.f), -127.f));
        acc += b0 + b1 + b2 + b3;
        o[c] = (b0 & 255) | ((b1 & 255) << 8) | ((b2 & 255) << 16) | ((b3 & 255) << 24);
    }
    xq[(size_t)row * 256 + t] = make_int4(o[0], o[1], o[2], o[3]);
#pragma unroll
    for (int off = 32; off >= 1; off >>= 1) acc += __shfl_down(acc, off);
    if ((t & 63) == 0) sred[t >> 6] = acc;
    __syncthreads();
    if (t == 0) rs[row] = (float)(sred[0] + sred[1] + sred[2] + sred[3]);
}

// ---------- pre-pass 2: qweight int32 (0..15) -> packed i8 ----------
__global__ __launch_bounds__(256) void k_pack_w(const int4* __restrict__ q, int4* __restrict__ wq) {
    size_t i = (size_t)blockIdx.x * 256 + threadIdx.x;   // 16 elems per thread
    int4 a = q[i * 4], b = q[i * 4 + 1], c = q[i * 4 + 2], d = q[i * 4 + 3];
    int4 o;
    o.x = a.x | (a.y << 8) | (a.z << 16) | (a.w << 24);
    o.y = b.x | (b.y << 8) | (b.z << 16) | (b.w << 24);
    o.z = c.x | (c.y << 8) | (c.z << 16) | (c.w << 24);
    o.w = d.x | (d.y << 8) | (d.z << 16) | (d.w << 24);
    wq[i] = o;
}

// ---------- 256x256 i8 GEMM, BK=128, 16x16x64 -- R14: best of 14 measured variants ----------
// S[m][n] = sum_k X[m][k]*Q[n][k] (exact);  y = (s/20)*S - (s*zp/20)*RS[m] + bias
// Cross-window read pipelining: read groups issue at the END of the window whose MFMA
// cluster last uses their target regs (operands latch at MFMA issue; SB0 pins order):
//   P4(t): after Q(1,0) -> issue A0,B0,B1 of tile t+1 (16 ds_reads, buf^1)
//   P2(t): after Q(0,1) -> issue A1 of tile t       (8 ds_reads, buf)
// Counted drains: P1 lgkmcnt(4) [A0+B0 = oldest 12 of 16]; P2/P3 lgkmcnt(0).
// 4 barriers/tile; vmcnt(8) ring never drains mid-loop.
// Measured: k_gemm 413-422 us, MfmaUtil 38-39%, SQ_LDS_BANK_CONFLICT = 0.
using gcptr = const __attribute__((address_space(1))) void*;
using lptr  = __attribute__((address_space(3))) void*;
#define GLD16(gp, lp) __builtin_amdgcn_global_load_lds((gcptr)(gp), (lptr)(lp), 16, 0, 0)
#define BAR() asm volatile("s_barrier" ::: "memory")
#define SB0() __builtin_amdgcn_sched_barrier(0)
#define LGKM4() do { asm volatile("s_waitcnt lgkmcnt(4)" ::: "memory"); SB0(); } while (0)
#define LGKM0() do { asm volatile("s_waitcnt lgkmcnt(0)" ::: "memory"); SB0(); } while (0)
#define VMW8() asm volatile("s_waitcnt vmcnt(8)" ::: "memory")
#define VMW0() asm volatile("s_waitcnt vmcnt(0)" ::: "memory")

__global__ __launch_bounds__(512, 2) void k_gemm(const uchar* __restrict__ A,
                                                 const uchar* __restrict__ B,
                                                 const float* __restrict__ rs,
                                                 const float* __restrict__ sc,
                                                 const float* __restrict__ zp,
                                                 const float* __restrict__ bias,
                                                 float* __restrict__ C) {
    constexpr int NT = K_DIM / 128;             // 32 K-tiles of BK=128 bytes
    constexpr int NBM = M_DIM / 256;            // 32
    constexpr int NWG = NBM * (N_DIM / 256);    // 1376, % 8 == 0

    __shared__ uchar sA[2][256 * 128];          // 2 x 32 KB
    __shared__ uchar sB[2][256 * 128];          // 2 x 32 KB  (128 KB total)

    // XCD-aware bijective swizzle
    int id = (blockIdx.x & 7) * (NWG / 8) + (blockIdx.x >> 3);
    const int bm = id & (NBM - 1);
    const int bn = id >> 5;

    const int tid = threadIdx.x;
    const int lane = tid & 63;
    const int w  = tid >> 6;     // wave 0..7
    const int wr = w >> 2;       // 0..1 (M)
    const int wc = w & 3;        // 0..3 (N)

    // ---- staging source (pre-swizzled global chunk: c_src = c_lds ^ (row&7), 16B chunks) ----
    const int trow = tid >> 3;                                   // 0..63
    const int scol = ((tid & 7) ^ (trow & 7)) * 16;              // byte col
    const uchar* aBase = A + (size_t)(bm * 256 + trow) * K_DIM + scol;
    const uchar* bBase = B + (size_t)(bn * 256 + trow) * K_DIM + scol;
    const int ldsW = w * 1024;                                   // wave-uniform dest (bytes)

#define STAGE_A(kt, H, sbuf) do { if ((kt) < NT) { \
        const uchar* _s = aBase + (size_t)((H) * 128) * K_DIM + (kt) * 128; \
        uchar* _d = &sA[sbuf][(H) * 16384 + ldsW]; \
        GLD16(_s, _d); GLD16(_s + (size_t)64 * K_DIM, _d + 8192); } } while (0)
#define STAGE_B(kt, H, sbuf) do { if ((kt) < NT) { \
        const uchar* _s = bBase + (size_t)((H) * 128) * K_DIM + (kt) * 128; \
        uchar* _d = &sB[sbuf][(H) * 16384 + ldsW]; \
        GLD16(_s, _d); GLD16(_s + (size_t)64 * K_DIM, _d + 8192); } } while (0)

    // ---- ds_read lane addressing (swizzled, 16-row frags; zero-conflict geometry) ----
    const int rowAb = (wr * 16 + (lane & 15)) * 128;   // byte offset of lane's row
    const int rowBb = (wc * 16 + (lane & 15)) * 128;
    const int cb  = lane >> 4;                         // chunk selector 0..3
    const int swz = lane & 7;                          // row&7 for this lane
#define CHUNK(ks) ((((ks) * 4 + cb) ^ swz) * 16)

    i32x4 aF[4][2];            // CURRENT A-half: 4 m-frags x 2 ks
    i32x4 bF[2][2][2];         // BOTH B-halves: nh x 2 ii x 2 ks
    i32x4 acc[8][4];           // 8 m-frags x 4 n-frags (16x16 each)
#pragma unroll
    for (int j = 0; j < 8; ++j)
#pragma unroll
        for (int i = 0; i < 4; ++i) acc[j][i] = (i32x4){0, 0, 0, 0};

#define LDA(mh, buf) do { \
    _Pragma("unroll") for (int jj = 0; jj < 4; ++jj) \
    _Pragma("unroll") for (int ks = 0; ks < 2; ++ks) \
        aF[jj][ks] = *(const i32x4*)&sA[buf][(mh) * 16384 + jj * 4096 + rowAb + CHUNK(ks)]; \
    } while (0)
#define LDB(nh, buf) do { \
    _Pragma("unroll") for (int ii = 0; ii < 2; ++ii) \
    _Pragma("unroll") for (int ks = 0; ks < 2; ++ks) \
        bF[nh][ii][ks] = *(const i32x4*)&sB[buf][(nh) * 16384 + ii * 8192 + rowBb + CHUNK(ks)]; \
    } while (0)
    // ks outer: 8 independent MFMAs then their ks=1 partners (dep distance 8)
#define MFMA_Q(mh, nh) do { \
    __builtin_amdgcn_s_setprio(1); \
    _Pragma("unroll") for (int ks = 0; ks < 2; ++ks) \
    _Pragma("unroll") for (int jj = 0; jj < 4; ++jj) \
    _Pragma("unroll") for (int ii = 0; ii < 2; ++ii) \
        acc[(mh) * 4 + jj][(nh) * 2 + ii] = __builtin_amdgcn_mfma_i32_16x16x64_i8( \
            aF[jj][ks], bF[nh][ii][ks], acc[(mh) * 4 + jj][(nh) * 2 + ii], 0, 0, 0); \
    __builtin_amdgcn_s_setprio(0); \
    SB0(); \
    } while (0)

    // ---- prologue: stage tiles 0,1 fully; publish t0; prime A0,B0,B1 of t0 ----
    STAGE_A(0, 0, 0); STAGE_B(0, 0, 0); STAGE_B(0, 1, 0); STAGE_A(0, 1, 0);
    STAGE_A(1, 0, 1); STAGE_B(1, 0, 1); STAGE_B(1, 1, 1); STAGE_A(1, 1, 1);
    VMW8();          // t0's 8 retired; t1's 8 in flight
    BAR();
    LDA(0, 0); LDB(0, 0);      // group 1: A0+B0 (12 reads)
    SB0();
    LDB(1, 0);                 // group 2: B1 (4 reads)  -- fenced: FIFO order matters

    // ---- main loop: 4 windows/tile, 4 barriers/tile, counted lgkm drains ----
#define GROUP(g, buf) do { \
    /* P1: Q(0,0). A0,B0 issued at P4(t-1) -- drain oldest 12, keep B1 in flight */ \
    LGKM4(); \
    MFMA_Q(0, 0); \
    BAR(); \
    /* P2: Q(0,1). B1 issued a full tile ago -- free drain. Then issue A1(t). */ \
    STAGE_A((g) + 2, 0, buf); STAGE_B((g) + 2, 0, buf); \
    LGKM0(); \
    MFMA_Q(0, 1); \
    LDA(1, buf);                       /* A1(t): aF regs free after Q(0,1) issue */ \
    BAR(); \
    /* P3: Q(1,1). A1 had P2-tail + stage to complete. */ \
    STAGE_B((g) + 2, 1, buf); \
    LGKM0(); \
    MFMA_Q(1, 1); \
    BAR(); \
    /* P4: publish t+1; Q(1,0); issue A0,B0,B1 of t+1 from buf^1 */ \
    STAGE_A((g) + 2, 1, buf); \
    if ((g) >= NT - 3) { VMW0(); } else { VMW8(); } \
    BAR(); \
    MFMA_Q(1, 0); \
    if ((g) + 1 < NT) { \
        LDA(0, (buf) ^ 1); LDB(0, (buf) ^ 1); \
        SB0(); \
        LDB(1, (buf) ^ 1); \
    } \
    } while (0)

    for (int g = 0; g < NT; g += 2) {
        GROUP(g, 0);
        GROUP(g + 1, 1);
    }

    // ---- epilogue: y = fs*S - fz*RS[row] + bias ----
    const float inv = 1.0f / XSCALE;
    float fsv[4], fzv[4], bvv[4];
    int colv[4];
#pragma unroll
    for (int i = 0; i < 4; ++i) {
        colv[i] = bn * 256 + 16 * wc + 64 * i + (lane & 15);
        fsv[i] = sc[colv[i]] * inv;
        fzv[i] = fsv[i] * zp[colv[i]];
        bvv[i] = bias[colv[i]];
    }
#pragma unroll
    for (int j = 0; j < 8; ++j) {
        const int rowbase = bm * 256 + 16 * wr + 32 * j + ((lane >> 4) << 2);
#pragma unroll
        for (int r = 0; r < 4; ++r) {
            const int row = rowbase + r;
            const float rsv = rs[row];
            float* cp = C + (size_t)row * N_DIM;
#pragma unroll
            for (int i = 0; i < 4; ++i)
                cp[colv[i]] = fsv[i] * (float)acc[j][i][r] - fzv[i] * rsv + bvv[i];
        }
    }
#undef GROUP
#undef MFMA_Q
#undef LDA
#undef LDB
#undef CHUNK
#undef STAGE_A
#undef STAGE_B
}

// ---------- fallback (ws too small): classic 16x16 fp32 tiled GEMM ----------
__global__ __launch_bounds__(256) void k_fb(const float* __restrict__ x, const int* __restrict__ q,
                                            const float* __restrict__ sc, const float* __restrict__ zp,
                                            const float* __restrict__ bias, float* __restrict__ C) {
    __shared__ float sX[16][17];
    __shared__ float sW[16][17];
    int tx = threadIdx.x & 15, ty = threadIdx.x >> 4;
    int m0 = blockIdx.y * 16, n0 = blockIdx.x * 16;
    int o = n0 + ty;
    float s = sc[o], z = zp[o];
    float acc = 0.f;
    for (int k0 = 0; k0 < K_DIM; k0 += 16) {
        sX[ty][tx] = x[(size_t)(m0 + ty) * K_DIM + k0 + tx];
        sW[ty][tx] = ((float)q[(size_t)o * K_DIM + k0 + tx] - z) * s;
        __syncthreads();
#pragma unroll
        for (int kk = 0; kk < 16; ++kk) acc += sX[ty][kk] * sW[tx][kk];
        __syncthreads();
    }
    C[(size_t)(m0 + ty) * N_DIM + n0 + tx] = acc + bias[n0 + tx];
}

extern "C" void kernel_launch(void* const* d_in, const int* in_sizes, int n_in,
                              void* d_out, int out_size, void* d_ws, size_t ws_size,
                              hipStream_t stream) {
    const float* x    = (const float*)d_in[0];
    const int*   qw   = (const int*)d_in[1];
    const float* sc   = (const float*)d_in[2];
    const float* zp   = (const float*)d_in[3];
    const float* bias = (const float*)d_in[4];
    float* out = (float*)d_out;

    const size_t xq_bytes = (size_t)M_DIM * K_DIM;        // 33,554,432
    const size_t wq_bytes = (size_t)N_DIM * K_DIM;        // 45,088,768
    const size_t rs_bytes = (size_t)M_DIM * 4;            // 32,768
    if (ws_size >= xq_bytes + wq_bytes + rs_bytes) {
        uchar* xq = (uchar*)d_ws;
        uchar* wq = xq + xq_bytes;
        float* rs = (float*)(wq + wq_bytes);
        k_quant_x<<<M_DIM, 256, 0, stream>>>((const float4*)x, (int4*)xq, rs);
        k_pack_w<<<N_DIM, 256, 0, stream>>>((const int4*)qw, (int4*)wq);
        k_gemm<<<(M_DIM / 256) * (N_DIM / 256), 512, 0, stream>>>(xq, wq, rs, sc, zp, bias, out);
    } else {
        dim3 g(N_DIM / 16, M_DIM / 16);
        k_fb<<<g, 256, 0, stream>>>(x, qw, sc, zp, bias, out);
    }
}